// Round 19
// baseline (837.295 us; speedup 1.0000x reference)
//
#include <hip/hip_runtime.h>
#include <stdint.h>

// Problem dims (fixed by the reference)
#define TT 256
#define SS 256
#define FF 1024
#define AA 256

typedef __attribute__((ext_vector_type(8))) short short8;
typedef __attribute__((ext_vector_type(8))) unsigned short ushort8v;
typedef __attribute__((ext_vector_type(4))) float floatx4;

// fp32 -> bf16 round-to-nearest-even
__device__ __forceinline__ unsigned short f2bf(float f) {
  unsigned int u = __float_as_uint(f);
  u += 0x7FFFu + ((u >> 16) & 1u);
  return (unsigned short)(u >> 16);
}

// async global->LDS, 16 B per lane; LDS dest = wave-uniform base + lane*16
__device__ __forceinline__ void gl_lds16(const unsigned short* g, unsigned short* l) {
  __builtin_amdgcn_global_load_lds(
      (__attribute__((address_space(1))) void*)(g),
      (__attribute__((address_space(3))) void*)(l), 16, 0, 0);
}

// swizzled LDS fragment read: logical (row, 16B-chunk lq) of a [R][32] bf16
// tile; phys byte = logical ^ ((bit9)<<5)  (st_16x32; 0 conflicts measured
// at this 64B row stride — do NOT reuse for other strides, see R7 lesson)
__device__ __forceinline__ short8 frag_ld(const unsigned short* base, int row,
                                          int lq) {
  unsigned l = (unsigned)(row * 64 + lq * 16);
  l ^= ((l >> 9) & 1u) << 5;
  return *(const short8*)((const char*)base + l);
}

// ---------------------------------------------------------------------------
// Fused prep: ONE launch does batch fp32->bf16 cvt (blocks 0..2047) and the
// three weight transposes WT[n][k] = bf16(W[k][n]) (blocks 2048..3583).
// ---------------------------------------------------------------------------
__global__ __launch_bounds__(256) void k_prep(
    const float* __restrict__ batch, const float* __restrict__ a_w,
    const float* __restrict__ b_w, const float* __restrict__ g_w,
    unsigned short* __restrict__ aT, unsigned short* __restrict__ bT,
    unsigned short* __restrict__ gT, unsigned short* __restrict__ batch16) {
  __shared__ float tile[32][33];
  const int b = blockIdx.x;
  const int tid = threadIdx.x;

  if (b < 2048) {
    const long n8 = (long)TT * SS * FF / 8;
    long i = (long)b * 256 + tid;
    const long stride = 2048L * 256;
    for (; i < n8; i += stride) {
      const floatx4 v0 = *(const floatx4*)(batch + i * 8);
      const floatx4 v1 = *(const floatx4*)(batch + i * 8 + 4);
      ushort8v h;
      h[0] = f2bf(v0.x); h[1] = f2bf(v0.y); h[2] = f2bf(v0.z); h[3] = f2bf(v0.w);
      h[4] = f2bf(v1.x); h[5] = f2bf(v1.y); h[6] = f2bf(v1.z); h[7] = f2bf(v1.w);
      *(ushort8v*)(batch16 + i * 8) = h;
    }
    return;
  }

  int tb = b - 2048;
  const float* W;
  unsigned short* WT;
  int N, bk, bn;
  if (tb < 256)      { W = a_w; WT = aT; N = AA; bk = (tb & 31) * 32; bn = (tb >> 5) * 32; }
  else if (tb < 512) { tb -= 256; W = b_w; WT = bT; N = AA; bk = (tb & 31) * 32; bn = (tb >> 5) * 32; }
  else               { tb -= 512; W = g_w; WT = gT; N = FF; bk = (tb & 31) * 32; bn = (tb >> 5) * 32; }
  const int K = FF;
  const int tx = tid & 31, ty = tid >> 5;
  for (int i = ty; i < 32; i += 8)
    tile[i][tx] = W[(size_t)(bk + i) * N + bn + tx];
  __syncthreads();
  for (int i = ty; i < 32; i += 8)
    WT[(size_t)(bn + i) * K + bk + tx] = f2bf(tile[tx][i]);
}

// ---------------------------------------------------------------------------
// Weight transpose (fallback path only).
// ---------------------------------------------------------------------------
__global__ void k_transpose_cvt(const float* __restrict__ W,
                                unsigned short* __restrict__ WT,
                                int K, int N) {
  __shared__ float tile[32][33];
  const int bk = blockIdx.x * 32, bn = blockIdx.y * 32;
  const int tx = threadIdx.x, ty = threadIdx.y;
  for (int i = ty; i < 32; i += 8)
    tile[i][tx] = W[(size_t)(bk + i) * N + bn + tx];
  __syncthreads();
  for (int i = ty; i < 32; i += 8)
    WT[(size_t)(bn + i) * K + bk + tx] = f2bf(tile[tx][i]);
}

// ---------------------------------------------------------------------------
// Projection GEMM, 256x256 tile. R19: 2-SLOT ring (64 KB LDS) -> 2 blocks/CU
// (16 waves/CU; cross-block stall hiding at UNCHANGED tile size — the clean
// occupancy test R10 confounded by shrinking the tile). Schedule = k_bt256's
// verified loop (R18-proven numerics): per K-tile {STG(other slot, next) ||
// read frags(cur) -> lgkm0 -> 32 MFMA -> vmcnt(0)+barrier}. Slot written at
// iter j was read at j-1 before its closing barrier -> safe. Swizzle/frag
// patterns byte-identical to the verified ones (0 conflicts).
// ---------------------------------------------------------------------------
__global__ __launch_bounds__(512, 2) void k_proj8(
    const unsigned short* __restrict__ batch16,
    const unsigned short* __restrict__ aT,
    const unsigned short* __restrict__ bT,
    const unsigned short* __restrict__ gT,
    const float* __restrict__ a_b, const float* __restrict__ b_b,
    const float* __restrict__ g_b,
    unsigned short* __restrict__ theta,
    unsigned short* __restrict__ phi,
    unsigned short* __restrict__ featsT) {
  const int K = FF;  // 1024
  __shared__ unsigned short Al[2][2][4096];  // [slot][m-half][128*32] 32 KB
  __shared__ unsigned short Bl[2][2][4096];  // [slot][n-half][128*32] 32 KB

  const int lin = blockIdx.x;
  const int xcd = lin & 7, idx = lin >> 3;
  const int nt = idx % 6;
  const int mt = xcd * 32 + idx / 6;
  const int m0 = mt * 256;

  const unsigned short* Wt;
  const float* bias;
  int mode, nf0 = 0;  // mode: 0 theta, 1 phi, 2 featsT
  if (nt == 0)      { Wt = aT; bias = a_b; mode = 0; }
  else if (nt == 1) { Wt = bT; bias = b_b; mode = 1; }
  else { nf0 = (nt - 2) * 256; Wt = gT + (size_t)nf0 * K; bias = g_b + nf0; mode = 2; }

  const int tid = threadIdx.x;
  const int lane = tid & 63, wave = tid >> 6;
  const int wm = wave >> 2, wn = wave & 3;   // 2 x 4 wave grid
  const int lr = lane & 15, lq = lane >> 4;
  const int bh = wn >> 1;                    // which B half this wave reads
  const int bn0 = (wn & 1) * 64;             // row base within B half

  const unsigned o = (unsigned)tid * 16u;
  const unsigned lo = o ^ (((o >> 9) & 1u) << 5);
  const int srow = (int)(lo >> 6);          // 0..127
  const int scol = (int)((lo & 63u) >> 1);  // 0..24 step 8
  const unsigned aoff = (unsigned)(srow * K + scol);  // 32-bit lane offset
  const int ldsb = wave * 512;              // wave-uniform dest base (elems)

  const unsigned short* pA0 = batch16 + (size_t)m0 * K;
  const unsigned short* pA1 = pA0 + (size_t)128 * K;
  const unsigned short* pB0 = Wt;
  const unsigned short* pB1 = Wt + (size_t)128 * K;

  floatx4 acc[8][4];
#pragma unroll
  for (int i = 0; i < 8; i++)
#pragma unroll
    for (int j = 0; j < 4; j++) acc[i][j] = (floatx4)0.0f;

#define STG1(s_, k_)                                   \
  do {                                                 \
    gl_lds16(pA0 + aoff + (k_), &Al[s_][0][ldsb]);     \
    gl_lds16(pA1 + aoff + (k_), &Al[s_][1][ldsb]);     \
    gl_lds16(pB0 + aoff + (k_), &Bl[s_][0][ldsb]);     \
    gl_lds16(pB1 + aoff + (k_), &Bl[s_][1][ldsb]);     \
  } while (0)

  STG1(0, 0);
  asm volatile("s_waitcnt vmcnt(0)" ::: "memory");
  __builtin_amdgcn_s_barrier();

  for (int j = 0; j < 32; ++j) {
    const int cur = j & 1;
    if (j < 31) STG1(cur ^ 1, (j + 1) * 32);  // other slot: reads done at j-1

    const unsigned short* Ah = Al[cur][wm];
    const unsigned short* Bh = Bl[cur][bh];
    short8 fA[8], fB[4];
#pragma unroll
    for (int i = 0; i < 8; i++)
      fA[i] = frag_ld(Ah, ((i >> 2) * 64) + (i & 3) * 16 + lr, lq);
#pragma unroll
    for (int i = 0; i < 4; i++)
      fB[i] = frag_ld(Bh, bn0 + i * 16 + lr, lq);
    asm volatile("s_waitcnt lgkmcnt(0)" ::: "memory");
    __builtin_amdgcn_sched_barrier(0);

    __builtin_amdgcn_s_setprio(1);
#pragma unroll
    for (int i = 0; i < 8; i++)
#pragma unroll
      for (int jj = 0; jj < 4; jj++)
        acc[i][jj] = __builtin_amdgcn_mfma_f32_16x16x32_bf16(fA[i], fB[jj],
                                                             acc[i][jj], 0, 0, 0);
    __builtin_amdgcn_s_setprio(0);

    if (j < 31) {
      asm volatile("s_waitcnt vmcnt(0)" ::: "memory");  // stages ~1300cy old
      __builtin_amdgcn_s_barrier();
    }
  }
#undef STG1

  // Epilogue. C/D layout: col = lane&15 (lr), row = lq*4 + rr.
  if (mode == 2) {
#pragma unroll
    for (int r = 0; r < 8; r++) {
      const int s0 = wm * 128 + r * 16 + lq * 4;  // s (within t), 4 contiguous
#pragma unroll
      for (int jj = 0; jj < 4; jj++) {
        const int cl = wn * 64 + jj * 16 + lr;
        const float bv = bias[cl];
        ushort4 h;
        h.x = f2bf(acc[r][jj][0] + bv);
        h.y = f2bf(acc[r][jj][1] + bv);
        h.z = f2bf(acc[r][jj][2] + bv);
        h.w = f2bf(acc[r][jj][3] + bv);
        *(ushort4*)&featsT[((size_t)mt * FF + nf0 + cl) * SS + s0] = h;
      }
    }
  } else {
    unsigned short* outp = (mode == 0) ? theta : phi;
#pragma unroll
    for (int r = 0; r < 8; r++) {
      const int row0 = m0 + wm * 128 + r * 16 + lq * 4;
#pragma unroll
      for (int jj = 0; jj < 4; jj++) {
        const int col = wn * 64 + jj * 16 + lr;
        const float bv = bias[col];
#pragma unroll
        for (int rr = 0; rr < 4; rr++)
          outp[(size_t)(row0 + rr) * AA + col] = f2bf(acc[r][jj][rr] + bv);
      }
    }
  }
}

// ---------------------------------------------------------------------------
// Fused projection GEMM, fp32-A FALLBACK (used only if workspace too small).
// ---------------------------------------------------------------------------
__global__ __launch_bounds__(256) void k_proj(
    const float* __restrict__ batch,
    const unsigned short* __restrict__ aT,
    const unsigned short* __restrict__ bT,
    const unsigned short* __restrict__ gT,
    const float* __restrict__ a_b, const float* __restrict__ b_b,
    const float* __restrict__ g_b,
    unsigned short* __restrict__ theta,
    unsigned short* __restrict__ phi,
    unsigned short* __restrict__ featsT) {
  const int K = FF;
  __shared__ unsigned short As[128 * 32];
  __shared__ unsigned short Bs[128 * 32];

  const int nt = blockIdx.x, mt = blockIdx.y;
  const int m0 = mt * 128;
  const unsigned short* Wt;
  const float* bias;
  int nloc0, mode;
  if (nt < 2)      { Wt = aT; bias = a_b; nloc0 = nt * 128;       mode = 0; }
  else if (nt < 4) { Wt = bT; bias = b_b; nloc0 = (nt - 2) * 128; mode = 1; }
  else             { Wt = gT; bias = g_b; nloc0 = (nt - 4) * 128; mode = 2; }

  const int tid = threadIdx.x;
  const int lane = tid & 63, wave = tid >> 6;
  const int wm = wave >> 1, wn = wave & 1;
  const int lr = lane & 15, lq = lane >> 4;

  floatx4 acc[4][4];
#pragma unroll
  for (int i = 0; i < 4; i++)
#pragma unroll
    for (int j = 0; j < 4; j++) acc[i][j] = (floatx4)0.0f;

  for (int k0 = 0; k0 < K; k0 += 32) {
    __syncthreads();
    {
      int sl = tid;
      gl_lds16(Wt + (size_t)(nloc0 + (sl >> 2)) * K + k0 + (sl & 3) * 8,
               &Bs[wave * 512]);
      sl = tid + 256;
      gl_lds16(Wt + (size_t)(nloc0 + (sl >> 2)) * K + k0 + (sl & 3) * 8,
               &Bs[2048 + wave * 512]);
    }
#pragma unroll
    for (int sgi = 0; sgi < 4; sgi++) {
      int g = sgi * 256 + tid;
      int row = g >> 3, c4 = g & 7;
      const floatx4 v =
          *(const floatx4*)(batch + (size_t)(m0 + row) * K + k0 + c4 * 4);
      ushort4 h;
      h.x = f2bf(v.x); h.y = f2bf(v.y); h.z = f2bf(v.z); h.w = f2bf(v.w);
      *(ushort4*)&As[row * 32 + c4 * 4] = h;
    }
    __syncthreads();

    short8 af[4], bfr[4];
#pragma unroll
    for (int i = 0; i < 4; i++)
      af[i] = *(const short8*)&As[(wm * 64 + i * 16 + lr) * 32 + lq * 8];
#pragma unroll
    for (int j = 0; j < 4; j++)
      bfr[j] = *(const short8*)&Bs[(wn * 64 + j * 16 + lr) * 32 + lq * 8];
#pragma unroll
    for (int i = 0; i < 4; i++)
#pragma unroll
      for (int j = 0; j < 4; j++)
        acc[i][j] = __builtin_amdgcn_mfma_f32_16x16x32_bf16(af[i], bfr[j],
                                                            acc[i][j], 0, 0, 0);
  }

#pragma unroll
  for (int i = 0; i < 4; i++) {
    const int row0 = wm * 64 + i * 16 + lq * 4;
#pragma unroll
    for (int j = 0; j < 4; j++) {
      const int col = wn * 64 + j * 16 + lr;
      const float bv = bias[nloc0 + col];
      if (mode == 2) {
        const int m = m0 + row0;
        const int t = m >> 8, s = m & 255;
        ushort4 h;
        h.x = f2bf(acc[i][j][0] + bv);
        h.y = f2bf(acc[i][j][1] + bv);
        h.z = f2bf(acc[i][j][2] + bv);
        h.w = f2bf(acc[i][j][3] + bv);
        *(ushort4*)&featsT[((size_t)t * FF + nloc0 + col) * SS + s] = h;
      } else {
        unsigned short* outp = (mode == 0) ? theta : phi;
#pragma unroll
        for (int rr = 0; rr < 4; rr++)
          outp[(size_t)(m0 + row0 + rr) * AA + nloc0 + col] =
              f2bf(acc[i][j][rr] + bv);
      }
    }
  }
}

// ---------------------------------------------------------------------------
// Fused attn+apply v2 (R8/R11 VERIFIED — primary path):
//   Phase 1: P = theta[t][mh*128..][:] @ phi[t]^T  (128x256 bf16 -> LDS P)
//   Phase 2: out = P @ featsT[t]^T / 512           (3-slot ring, vmcnt(2));
//            wait SKIPPED at T%8 in {0,1}, T>=8 (chunk-end store-queue proof).
// ---------------------------------------------------------------------------
__global__ __launch_bounds__(512) void k_fused2(
    const unsigned short* __restrict__ theta,
    const unsigned short* __restrict__ phi,
    const unsigned short* __restrict__ featsT,
    float* __restrict__ out) {
  __shared__ unsigned short ring[24576];   // 48 KB
  __shared__ unsigned short P[128 * 256];  // 64 KB, swizzled

  const int lin = blockIdx.x;
  const int xcd = lin & 7, idx = lin >> 3;  // idx in [0,64)
  const int t = xcd * 32 + (idx >> 1);
  const int mh = idx & 1;

  const int tid = threadIdx.x, lane = tid & 63, wave = tid >> 6;
  const int wm = wave >> 2, wn = wave & 3;  // 2 x 4 wave grid
  const int lr = lane & 15, lq = lane >> 4;

  const unsigned short* Ath = theta + ((size_t)t * SS + mh * 128) * AA;
  const unsigned short* Bph = phi + (size_t)t * SS * AA;
  const unsigned short* Bft = featsT + (size_t)t * FF * SS;

  const unsigned o = (unsigned)tid * 16u;
  const unsigned lo = o ^ (((o >> 9) & 1u) << 5);
  const int srow = (int)(lo >> 6);          // 0..127
  const int scol = (int)((lo & 63u) >> 1);  // 0..24 step 8
  const int ldsb = wave * 512;              // elems

#define STG_P1(s_, k_)                                                       \
  do {                                                                       \
    gl_lds16(Ath + (size_t)srow * AA + (k_) + scol, &ring[(s_)*12288 + ldsb]); \
    gl_lds16(Bph + (size_t)srow * AA + (k_) + scol,                          \
             &ring[(s_)*12288 + 4096 + ldsb]);                               \
    gl_lds16(Bph + (size_t)(128 + srow) * AA + (k_) + scol,                  \
             &ring[(s_)*12288 + 8192 + ldsb]);                               \
  } while (0)

  floatx4 acc[4][4];
#pragma unroll
  for (int i = 0; i < 4; i++)
#pragma unroll
    for (int j = 0; j < 4; j++) acc[i][j] = (floatx4)0.0f;

  STG_P1(0, 0);
  STG_P1(1, 32);
  for (int k = 0; k < 8; ++k) {
    if (k < 7)
      asm volatile("s_waitcnt vmcnt(3)" ::: "memory");  // tile k landed
    else
      asm volatile("s_waitcnt vmcnt(0)" ::: "memory");
    __builtin_amdgcn_s_barrier();

    const unsigned short* Abase = &ring[(k & 1) * 12288];
    const unsigned short* Bbase = Abase + 4096;
    short8 af[4], bf4[4];
#pragma unroll
    for (int i = 0; i < 4; i++)
      af[i] = frag_ld(Abase, wm * 64 + i * 16 + lr, lq);
#pragma unroll
    for (int j = 0; j < 4; j++)
      bf4[j] = frag_ld(Bbase, wn * 64 + j * 16 + lr, lq);
    asm volatile("s_waitcnt lgkmcnt(0)" ::: "memory");
    __builtin_amdgcn_s_barrier();
    if (k + 2 < 8) STG_P1(k & 1, (k + 2) * 32);

    __builtin_amdgcn_s_setprio(1);
#pragma unroll
    for (int i = 0; i < 4; i++)
#pragma unroll
      for (int j = 0; j < 4; j++)
        acc[i][j] = __builtin_amdgcn_mfma_f32_16x16x32_bf16(af[i], bf4[j],
                                                            acc[i][j], 0, 0, 0);
    __builtin_amdgcn_s_setprio(0);
  }
#undef STG_P1

#pragma unroll
  for (int i = 0; i < 4; i++) {
#pragma unroll
    for (int j = 0; j < 4; j++) {
      const int colP = wn * 64 + j * 16 + lr;
#pragma unroll
      for (int rr = 0; rr < 4; rr++) {
        const int rowP = wm * 64 + i * 16 + lq * 4 + rr;
        const unsigned off =
            ((unsigned)(rowP * 256 + colP) * 2u) ^ ((unsigned)(rowP & 7) << 4);
        *(unsigned short*)((char*)P + off) = f2bf(acc[i][j][rr]);
      }
    }
  }
  __syncthreads();  // P published; all phase-1 ring reads complete

#define STG_P2(slot_, T_)                                                    \
  do {                                                                       \
    const int c_ = (T_) >> 3, k_ = ((T_)&7) * 32;                            \
    gl_lds16(Bft + (size_t)(c_ * 256 + srow) * SS + k_ + scol,               \
             &ring[(slot_)*8192 + ldsb]);                                    \
    gl_lds16(Bft + (size_t)(c_ * 256 + 128 + srow) * SS + k_ + scol,         \
             &ring[(slot_)*8192 + 4096 + ldsb]);                             \
  } while (0)

  STG_P2(0, 0);
  STG_P2(1, 1);

  const float inv = 1.0f / 512.0f;
  float* Ob = out + ((size_t)t * SS + mh * 128) * FF;

#pragma unroll
  for (int i = 0; i < 4; i++)
#pragma unroll
    for (int j = 0; j < 4; j++) acc[i][j] = (floatx4)0.0f;

  int slot = 0, slot2 = 2;
  for (int T = 0; T < 32; ++T) {
    if (T == 31) {
      asm volatile("s_waitcnt vmcnt(0)" ::: "memory");
    } else if (!(T >= 8 && (T & 7) < 2)) {
      asm volatile("s_waitcnt vmcnt(2)" ::: "memory");  // tile T landed
    }
    // else: skip — chunk-end stores guarantee STG(T) retired
    __builtin_amdgcn_s_barrier();

    const int k0 = (T & 7) * 32;
    const unsigned short* Bbase = &ring[slot * 8192];
    short8 af[4], bf4[4];
#pragma unroll
    for (int i = 0; i < 4; i++) {
      const int rowP = wm * 64 + i * 16 + lr;
      const unsigned off = ((unsigned)(rowP * 256 + k0 + lq * 8) * 2u) ^
                           ((unsigned)(rowP & 7) << 4);
      af[i] = *(const short8*)((const char*)P + off);
    }
#pragma unroll
    for (int j = 0; j < 4; j++)
      bf4[j] = frag_ld(Bbase, wn * 64 + j * 16 + lr, lq);
    if (T + 2 < 32) STG_P2(slot2, T + 2);

    __builtin_amdgcn_s_setprio(1);
#pragma unroll
    for (int i = 0; i < 4; i++)
#pragma unroll
      for (int j = 0; j < 4; j++)
        acc[i][j] = __builtin_amdgcn_mfma_f32_16x16x32_bf16(af[i], bf4[j],
                                                            acc[i][j], 0, 0, 0);
    __builtin_amdgcn_s_setprio(0);

    if ((T & 7) == 7) {  // f-chunk complete: write out, reset acc
      const int c = T >> 3;
#pragma unroll
      for (int i = 0; i < 4; i++) {
        const int row0 = wm * 64 + i * 16 + lq * 4;
#pragma unroll
        for (int j = 0; j < 4; j++) {
          const int col = c * 256 + wn * 64 + j * 16 + lr;
#pragma unroll
          for (int rr = 0; rr < 4; rr++)
            Ob[(size_t)(row0 + rr) * FF + col] = acc[i][j][rr] * inv;
          acc[i][j] = (floatx4)0.0f;
        }
      }
    }
    slot = (slot == 2) ? 0 : slot + 1;
    slot2 = (slot2 == 2) ? 0 : slot2 + 1;
  }
#undef STG_P2
}

// ---------------------------------------------------------------------------
extern "C" void kernel_launch(void* const* d_in, const int* in_sizes, int n_in,
                              void* d_out, int out_size, void* d_ws,
                              size_t ws_size, hipStream_t stream) {
  const float* batch = (const float*)d_in[0];
  const float* a_w   = (const float*)d_in[1];
  const float* a_b   = (const float*)d_in[2];
  const float* b_w   = (const float*)d_in[3];
  const float* b_b   = (const float*)d_in[4];
  const float* g_w   = (const float*)d_in[5];
  const float* g_b   = (const float*)d_in[6];
  float* out = (float*)d_out;

  // Workspace layout (bf16 elements).
  unsigned short* ws      = (unsigned short*)d_ws;
  unsigned short* aT      = ws;                                  // 256x1024
  unsigned short* bT      = aT + (size_t)AA * FF;                // 256x1024
  unsigned short* gT      = bT + (size_t)AA * FF;                // 1024x1024
  unsigned short* theta   = gT + (size_t)FF * FF;                // 65536x256
  unsigned short* phi     = theta + (size_t)TT * SS * AA;        // 65536x256
  unsigned short* featsT  = phi + (size_t)TT * SS * AA;          // [t][f][s]
  unsigned short* batch16 = featsT + (size_t)TT * FF * SS;       // 65536x1024

  const size_t need_b16 =
      ((size_t)2 * AA * FF + (size_t)FF * FF + (size_t)2 * TT * SS * AA +
       (size_t)TT * FF * SS + (size_t)TT * SS * FF) *
      sizeof(unsigned short);

  if (ws_size >= need_b16) {
    // One fused prep launch, 2-blocks/CU proj8, fused attn+apply.
    k_prep<<<dim3(3584), 256, 0, stream>>>(batch, a_w, b_w, g_w, aT, bT, gT,
                                           batch16);
    k_proj8<<<dim3(1536), 512, 0, stream>>>(batch16, aT, bT, gT, a_b, b_b,
                                            g_b, theta, phi, featsT);
    k_fused2<<<dim3(512), 512, 0, stream>>>(theta, phi, featsT, out);
  } else {
    // Fallback: fp32 in-kernel staging (previous verified path).
    dim3 tb(32, 8);
    k_transpose_cvt<<<dim3(32, 8),  tb, 0, stream>>>(a_w, aT, FF, AA);
    k_transpose_cvt<<<dim3(32, 8),  tb, 0, stream>>>(b_w, bT, FF, AA);
    k_transpose_cvt<<<dim3(32, 32), tb, 0, stream>>>(g_w, gT, FF, FF);
    k_proj<<<dim3(12, 512), 256, 0, stream>>>(batch, aT, bT, gT, a_b, b_b,
                                              g_b, theta, phi, featsT);
    k_fused2<<<dim3(512), 512, 0, stream>>>(theta, phi, featsT, out);
  }
}

// Round 20
// 775.768 us; speedup vs baseline: 1.0793x; 1.0793x over previous
//
#include <hip/hip_runtime.h>
#include <stdint.h>

// Problem dims (fixed by the reference)
#define TT 256
#define SS 256
#define FF 1024
#define AA 256

typedef __attribute__((ext_vector_type(8))) short short8;
typedef __attribute__((ext_vector_type(8))) unsigned short ushort8v;
typedef __attribute__((ext_vector_type(4))) float floatx4;

// fp32 -> bf16 round-to-nearest-even
__device__ __forceinline__ unsigned short f2bf(float f) {
  unsigned int u = __float_as_uint(f);
  u += 0x7FFFu + ((u >> 16) & 1u);
  return (unsigned short)(u >> 16);
}

// async global->LDS, 16 B per lane; LDS dest = wave-uniform base + lane*16
__device__ __forceinline__ void gl_lds16(const unsigned short* g, unsigned short* l) {
  __builtin_amdgcn_global_load_lds(
      (__attribute__((address_space(1))) void*)(g),
      (__attribute__((address_space(3))) void*)(l), 16, 0, 0);
}

// swizzled LDS fragment read: logical (row, 16B-chunk lq) of a [R][32] bf16
// tile; phys byte = logical ^ ((bit9)<<5)  (st_16x32; 0 conflicts measured
// at this 64B row stride — do NOT reuse for other strides, see R7 lesson)
__device__ __forceinline__ short8 frag_ld(const unsigned short* base, int row,
                                          int lq) {
  unsigned l = (unsigned)(row * 64 + lq * 16);
  l ^= ((l >> 9) & 1u) << 5;
  return *(const short8*)((const char*)base + l);
}

// ---------------------------------------------------------------------------
// Fused prep: ONE launch does batch fp32->bf16 cvt (blocks 0..2047) and the
// three weight transposes WT[n][k] = bf16(W[k][n]) (blocks 2048..3583).
// ---------------------------------------------------------------------------
__global__ __launch_bounds__(256) void k_prep(
    const float* __restrict__ batch, const float* __restrict__ a_w,
    const float* __restrict__ b_w, const float* __restrict__ g_w,
    unsigned short* __restrict__ aT, unsigned short* __restrict__ bT,
    unsigned short* __restrict__ gT, unsigned short* __restrict__ batch16) {
  __shared__ float tile[32][33];
  const int b = blockIdx.x;
  const int tid = threadIdx.x;

  if (b < 2048) {
    const long n8 = (long)TT * SS * FF / 8;
    long i = (long)b * 256 + tid;
    const long stride = 2048L * 256;
    for (; i < n8; i += stride) {
      const floatx4 v0 = *(const floatx4*)(batch + i * 8);
      const floatx4 v1 = *(const floatx4*)(batch + i * 8 + 4);
      ushort8v h;
      h[0] = f2bf(v0.x); h[1] = f2bf(v0.y); h[2] = f2bf(v0.z); h[3] = f2bf(v0.w);
      h[4] = f2bf(v1.x); h[5] = f2bf(v1.y); h[6] = f2bf(v1.z); h[7] = f2bf(v1.w);
      *(ushort8v*)(batch16 + i * 8) = h;
    }
    return;
  }

  int tb = b - 2048;
  const float* W;
  unsigned short* WT;
  int N, bk, bn;
  if (tb < 256)      { W = a_w; WT = aT; N = AA; bk = (tb & 31) * 32; bn = (tb >> 5) * 32; }
  else if (tb < 512) { tb -= 256; W = b_w; WT = bT; N = AA; bk = (tb & 31) * 32; bn = (tb >> 5) * 32; }
  else               { tb -= 512; W = g_w; WT = gT; N = FF; bk = (tb & 31) * 32; bn = (tb >> 5) * 32; }
  const int K = FF;
  const int tx = tid & 31, ty = tid >> 5;
  for (int i = ty; i < 32; i += 8)
    tile[i][tx] = W[(size_t)(bk + i) * N + bn + tx];
  __syncthreads();
  for (int i = ty; i < 32; i += 8)
    WT[(size_t)(bn + i) * K + bk + tx] = f2bf(tile[tx][i]);
}

// ---------------------------------------------------------------------------
// Weight transpose (fallback path only).
// ---------------------------------------------------------------------------
__global__ void k_transpose_cvt(const float* __restrict__ W,
                                unsigned short* __restrict__ WT,
                                int K, int N) {
  __shared__ float tile[32][33];
  const int bk = blockIdx.x * 32, bn = blockIdx.y * 32;
  const int tx = threadIdx.x, ty = threadIdx.y;
  for (int i = ty; i < 32; i += 8)
    tile[i][tx] = W[(size_t)(bk + i) * N + bn + tx];
  __syncthreads();
  for (int i = ty; i < 32; i += 8)
    WT[(size_t)(bn + i) * K + bk + tx] = f2bf(tile[tx][i]);
}

// ---------------------------------------------------------------------------
// Projection GEMM, 256x256 tile, 2-K-tiles-per-barrier pipeline
// (R11 VERIFIED VERSION — session-best; ~257 us, MfmaUtil 35%, 0 conflicts).
// 4-slot ring of verified [128][32] tiles (128 KB LDS); 16 iters x 2 K-tiles;
// one vmcnt(0)+barrier per iter (stages issued ~2300 cyc earlier).
// R19's 2-slot/64KB variant REVERTED: occupancy did NOT rise (still ~20%),
// barriers doubled -> 330 us. Occupancy limiter is not LDS here.
// ---------------------------------------------------------------------------
__global__ __launch_bounds__(512, 2) void k_proj8(
    const unsigned short* __restrict__ batch16,
    const unsigned short* __restrict__ aT,
    const unsigned short* __restrict__ bT,
    const unsigned short* __restrict__ gT,
    const float* __restrict__ a_b, const float* __restrict__ b_b,
    const float* __restrict__ g_b,
    unsigned short* __restrict__ theta,
    unsigned short* __restrict__ phi,
    unsigned short* __restrict__ featsT) {
  const int K = FF;  // 1024
  __shared__ unsigned short Al[4][2][4096];  // [slot][m-half][128*32] 64 KB
  __shared__ unsigned short Bl[4][2][4096];  // [slot][n-half][128*32] 64 KB

  const int lin = blockIdx.x;
  const int xcd = lin & 7, idx = lin >> 3;
  const int nt = idx % 6;
  const int mt = xcd * 32 + idx / 6;
  const int m0 = mt * 256;

  const unsigned short* Wt;
  const float* bias;
  int mode, nf0 = 0;  // mode: 0 theta, 1 phi, 2 featsT
  if (nt == 0)      { Wt = aT; bias = a_b; mode = 0; }
  else if (nt == 1) { Wt = bT; bias = b_b; mode = 1; }
  else { nf0 = (nt - 2) * 256; Wt = gT + (size_t)nf0 * K; bias = g_b + nf0; mode = 2; }

  const int tid = threadIdx.x;
  const int lane = tid & 63, wave = tid >> 6;
  const int wm = wave >> 2, wn = wave & 3;   // 2 x 4 wave grid
  const int lr = lane & 15, lq = lane >> 4;
  const int bh = wn >> 1;                    // which B half this wave reads
  const int bn0 = (wn & 1) * 64;             // row base within B half

  const unsigned o = (unsigned)tid * 16u;
  const unsigned lo = o ^ (((o >> 9) & 1u) << 5);
  const int srow = (int)(lo >> 6);          // 0..127
  const int scol = (int)((lo & 63u) >> 1);  // 0..24 step 8
  const unsigned aoff = (unsigned)(srow * K + scol);  // 32-bit lane offset
  const int ldsb = wave * 512;              // wave-uniform dest base (elems)

  const unsigned short* pA0 = batch16 + (size_t)m0 * K;
  const unsigned short* pA1 = pA0 + (size_t)128 * K;
  const unsigned short* pB0 = Wt;
  const unsigned short* pB1 = Wt + (size_t)128 * K;

  floatx4 acc[8][4];
#pragma unroll
  for (int i = 0; i < 8; i++)
#pragma unroll
    for (int j = 0; j < 4; j++) acc[i][j] = (floatx4)0.0f;

  short8 fA0[8], fB0[4], fA1[8], fB1[4];

#define STG1(s_, k_)                                   \
  do {                                                 \
    gl_lds16(pA0 + aoff + (k_), &Al[s_][0][ldsb]);     \
    gl_lds16(pA1 + aoff + (k_), &Al[s_][1][ldsb]);     \
    gl_lds16(pB0 + aoff + (k_), &Bl[s_][0][ldsb]);     \
    gl_lds16(pB1 + aoff + (k_), &Bl[s_][1][ldsb]);     \
  } while (0)

  STG1(0, 0);
  STG1(1, 32);
  asm volatile("s_waitcnt vmcnt(0)" ::: "memory");
  __builtin_amdgcn_s_barrier();

  for (int J = 0; J < 16; ++J) {
    const int s0 = (2 * J) & 3, s1 = (2 * J + 1) & 3;
    const unsigned short* A0h = Al[s0][wm];
    const unsigned short* B0h = Bl[s0][bh];
    const unsigned short* A1h = Al[s1][wm];
    const unsigned short* B1h = Bl[s1][bh];

#pragma unroll
    for (int i = 0; i < 8; i++)
      fA0[i] = frag_ld(A0h, ((i >> 2) * 64) + (i & 3) * 16 + lr, lq);
#pragma unroll
    for (int i = 0; i < 4; i++)
      fB0[i] = frag_ld(B0h, bn0 + i * 16 + lr, lq);
    if (J < 15) {
      STG1((2 * J + 2) & 3, (2 * J + 2) * 32);
      STG1((2 * J + 3) & 3, (2 * J + 3) * 32);
    }
    asm volatile("s_waitcnt lgkmcnt(0)" ::: "memory");
    __builtin_amdgcn_sched_barrier(0);

#pragma unroll
    for (int i = 0; i < 8; i++)
      fA1[i] = frag_ld(A1h, ((i >> 2) * 64) + (i & 3) * 16 + lr, lq);
#pragma unroll
    for (int i = 0; i < 4; i++)
      fB1[i] = frag_ld(B1h, bn0 + i * 16 + lr, lq);

    __builtin_amdgcn_s_setprio(1);
#pragma unroll
    for (int i = 0; i < 8; i++)
#pragma unroll
      for (int j = 0; j < 4; j++)
        acc[i][j] = __builtin_amdgcn_mfma_f32_16x16x32_bf16(fA0[i], fB0[j],
                                                            acc[i][j], 0, 0, 0);
    __builtin_amdgcn_s_setprio(0);
    asm volatile("s_waitcnt lgkmcnt(0)" ::: "memory");
    __builtin_amdgcn_sched_barrier(0);
    __builtin_amdgcn_s_setprio(1);
#pragma unroll
    for (int i = 0; i < 8; i++)
#pragma unroll
      for (int j = 0; j < 4; j++)
        acc[i][j] = __builtin_amdgcn_mfma_f32_16x16x32_bf16(fA1[i], fB1[j],
                                                            acc[i][j], 0, 0, 0);
    __builtin_amdgcn_s_setprio(0);

    if (J < 15) {
      asm volatile("s_waitcnt vmcnt(0)" ::: "memory");
      __builtin_amdgcn_s_barrier();
    }
  }
#undef STG1

  // Epilogue. C/D layout: col = lane&15 (lr), row = lq*4 + rr.
  if (mode == 2) {
#pragma unroll
    for (int r = 0; r < 8; r++) {
      const int s0 = wm * 128 + r * 16 + lq * 4;  // s (within t), 4 contiguous
#pragma unroll
      for (int jj = 0; jj < 4; jj++) {
        const int cl = wn * 64 + jj * 16 + lr;
        const float bv = bias[cl];
        ushort4 h;
        h.x = f2bf(acc[r][jj][0] + bv);
        h.y = f2bf(acc[r][jj][1] + bv);
        h.z = f2bf(acc[r][jj][2] + bv);
        h.w = f2bf(acc[r][jj][3] + bv);
        *(ushort4*)&featsT[((size_t)mt * FF + nf0 + cl) * SS + s0] = h;
      }
    }
  } else {
    unsigned short* outp = (mode == 0) ? theta : phi;
#pragma unroll
    for (int r = 0; r < 8; r++) {
      const int row0 = m0 + wm * 128 + r * 16 + lq * 4;
#pragma unroll
      for (int jj = 0; jj < 4; jj++) {
        const int col = wn * 64 + jj * 16 + lr;
        const float bv = bias[col];
#pragma unroll
        for (int rr = 0; rr < 4; rr++)
          outp[(size_t)(row0 + rr) * AA + col] = f2bf(acc[r][jj][rr] + bv);
      }
    }
  }
}

// ---------------------------------------------------------------------------
// Fused projection GEMM, fp32-A FALLBACK (used only if workspace too small).
// ---------------------------------------------------------------------------
__global__ __launch_bounds__(256) void k_proj(
    const float* __restrict__ batch,
    const unsigned short* __restrict__ aT,
    const unsigned short* __restrict__ bT,
    const unsigned short* __restrict__ gT,
    const float* __restrict__ a_b, const float* __restrict__ b_b,
    const float* __restrict__ g_b,
    unsigned short* __restrict__ theta,
    unsigned short* __restrict__ phi,
    unsigned short* __restrict__ featsT) {
  const int K = FF;
  __shared__ unsigned short As[128 * 32];
  __shared__ unsigned short Bs[128 * 32];

  const int nt = blockIdx.x, mt = blockIdx.y;
  const int m0 = mt * 128;
  const unsigned short* Wt;
  const float* bias;
  int nloc0, mode;
  if (nt < 2)      { Wt = aT; bias = a_b; nloc0 = nt * 128;       mode = 0; }
  else if (nt < 4) { Wt = bT; bias = b_b; nloc0 = (nt - 2) * 128; mode = 1; }
  else             { Wt = gT; bias = g_b; nloc0 = (nt - 4) * 128; mode = 2; }

  const int tid = threadIdx.x;
  const int lane = tid & 63, wave = tid >> 6;
  const int wm = wave >> 1, wn = wave & 1;
  const int lr = lane & 15, lq = lane >> 4;

  floatx4 acc[4][4];
#pragma unroll
  for (int i = 0; i < 4; i++)
#pragma unroll
    for (int j = 0; j < 4; j++) acc[i][j] = (floatx4)0.0f;

  for (int k0 = 0; k0 < K; k0 += 32) {
    __syncthreads();
    {
      int sl = tid;
      gl_lds16(Wt + (size_t)(nloc0 + (sl >> 2)) * K + k0 + (sl & 3) * 8,
               &Bs[wave * 512]);
      sl = tid + 256;
      gl_lds16(Wt + (size_t)(nloc0 + (sl >> 2)) * K + k0 + (sl & 3) * 8,
               &Bs[2048 + wave * 512]);
    }
#pragma unroll
    for (int sgi = 0; sgi < 4; sgi++) {
      int g = sgi * 256 + tid;
      int row = g >> 3, c4 = g & 7;
      const floatx4 v =
          *(const floatx4*)(batch + (size_t)(m0 + row) * K + k0 + c4 * 4);
      ushort4 h;
      h.x = f2bf(v.x); h.y = f2bf(v.y); h.z = f2bf(v.z); h.w = f2bf(v.w);
      *(ushort4*)&As[row * 32 + c4 * 4] = h;
    }
    __syncthreads();

    short8 af[4], bfr[4];
#pragma unroll
    for (int i = 0; i < 4; i++)
      af[i] = *(const short8*)&As[(wm * 64 + i * 16 + lr) * 32 + lq * 8];
#pragma unroll
    for (int j = 0; j < 4; j++)
      bfr[j] = *(const short8*)&Bs[(wn * 64 + j * 16 + lr) * 32 + lq * 8];
#pragma unroll
    for (int i = 0; i < 4; i++)
#pragma unroll
      for (int j = 0; j < 4; j++)
        acc[i][j] = __builtin_amdgcn_mfma_f32_16x16x32_bf16(af[i], bfr[j],
                                                            acc[i][j], 0, 0, 0);
  }

#pragma unroll
  for (int i = 0; i < 4; i++) {
    const int row0 = wm * 64 + i * 16 + lq * 4;
#pragma unroll
    for (int j = 0; j < 4; j++) {
      const int col = wn * 64 + j * 16 + lr;
      const float bv = bias[nloc0 + col];
      if (mode == 2) {
        const int m = m0 + row0;
        const int t = m >> 8, s = m & 255;
        ushort4 h;
        h.x = f2bf(acc[i][j][0] + bv);
        h.y = f2bf(acc[i][j][1] + bv);
        h.z = f2bf(acc[i][j][2] + bv);
        h.w = f2bf(acc[i][j][3] + bv);
        *(ushort4*)&featsT[((size_t)t * FF + nloc0 + col) * SS + s] = h;
      } else {
        unsigned short* outp = (mode == 0) ? theta : phi;
#pragma unroll
        for (int rr = 0; rr < 4; rr++)
          outp[(size_t)(m0 + row0 + rr) * AA + nloc0 + col] =
              f2bf(acc[i][j][rr] + bv);
      }
    }
  }
}

// ---------------------------------------------------------------------------
// Fused attn+apply v2 (R8/R11 VERIFIED — primary path):
//   Phase 1: P = theta[t][mh*128..][:] @ phi[t]^T  (128x256 bf16 -> LDS P)
//   Phase 2: out = P @ featsT[t]^T / 512           (3-slot ring, vmcnt(2));
//            wait SKIPPED at T%8 in {0,1}, T>=8 (chunk-end store-queue proof).
// ---------------------------------------------------------------------------
__global__ __launch_bounds__(512) void k_fused2(
    const unsigned short* __restrict__ theta,
    const unsigned short* __restrict__ phi,
    const unsigned short* __restrict__ featsT,
    float* __restrict__ out) {
  __shared__ unsigned short ring[24576];   // 48 KB
  __shared__ unsigned short P[128 * 256];  // 64 KB, swizzled

  const int lin = blockIdx.x;
  const int xcd = lin & 7, idx = lin >> 3;  // idx in [0,64)
  const int t = xcd * 32 + (idx >> 1);
  const int mh = idx & 1;

  const int tid = threadIdx.x, lane = tid & 63, wave = tid >> 6;
  const int wm = wave >> 2, wn = wave & 3;  // 2 x 4 wave grid
  const int lr = lane & 15, lq = lane >> 4;

  const unsigned short* Ath = theta + ((size_t)t * SS + mh * 128) * AA;
  const unsigned short* Bph = phi + (size_t)t * SS * AA;
  const unsigned short* Bft = featsT + (size_t)t * FF * SS;

  const unsigned o = (unsigned)tid * 16u;
  const unsigned lo = o ^ (((o >> 9) & 1u) << 5);
  const int srow = (int)(lo >> 6);          // 0..127
  const int scol = (int)((lo & 63u) >> 1);  // 0..24 step 8
  const int ldsb = wave * 512;              // elems

#define STG_P1(s_, k_)                                                       \
  do {                                                                       \
    gl_lds16(Ath + (size_t)srow * AA + (k_) + scol, &ring[(s_)*12288 + ldsb]); \
    gl_lds16(Bph + (size_t)srow * AA + (k_) + scol,                          \
             &ring[(s_)*12288 + 4096 + ldsb]);                               \
    gl_lds16(Bph + (size_t)(128 + srow) * AA + (k_) + scol,                  \
             &ring[(s_)*12288 + 8192 + ldsb]);                               \
  } while (0)

  floatx4 acc[4][4];
#pragma unroll
  for (int i = 0; i < 4; i++)
#pragma unroll
    for (int j = 0; j < 4; j++) acc[i][j] = (floatx4)0.0f;

  STG_P1(0, 0);
  STG_P1(1, 32);
  for (int k = 0; k < 8; ++k) {
    if (k < 7)
      asm volatile("s_waitcnt vmcnt(3)" ::: "memory");  // tile k landed
    else
      asm volatile("s_waitcnt vmcnt(0)" ::: "memory");
    __builtin_amdgcn_s_barrier();

    const unsigned short* Abase = &ring[(k & 1) * 12288];
    const unsigned short* Bbase = Abase + 4096;
    short8 af[4], bf4[4];
#pragma unroll
    for (int i = 0; i < 4; i++)
      af[i] = frag_ld(Abase, wm * 64 + i * 16 + lr, lq);
#pragma unroll
    for (int j = 0; j < 4; j++)
      bf4[j] = frag_ld(Bbase, wn * 64 + j * 16 + lr, lq);
    asm volatile("s_waitcnt lgkmcnt(0)" ::: "memory");
    __builtin_amdgcn_s_barrier();
    if (k + 2 < 8) STG_P1(k & 1, (k + 2) * 32);

    __builtin_amdgcn_s_setprio(1);
#pragma unroll
    for (int i = 0; i < 4; i++)
#pragma unroll
      for (int j = 0; j < 4; j++)
        acc[i][j] = __builtin_amdgcn_mfma_f32_16x16x32_bf16(af[i], bf4[j],
                                                            acc[i][j], 0, 0, 0);
    __builtin_amdgcn_s_setprio(0);
  }
#undef STG_P1

#pragma unroll
  for (int i = 0; i < 4; i++) {
#pragma unroll
    for (int j = 0; j < 4; j++) {
      const int colP = wn * 64 + j * 16 + lr;
#pragma unroll
      for (int rr = 0; rr < 4; rr++) {
        const int rowP = wm * 64 + i * 16 + lq * 4 + rr;
        const unsigned off =
            ((unsigned)(rowP * 256 + colP) * 2u) ^ ((unsigned)(rowP & 7) << 4);
        *(unsigned short*)((char*)P + off) = f2bf(acc[i][j][rr]);
      }
    }
  }
  __syncthreads();  // P published; all phase-1 ring reads complete

#define STG_P2(slot_, T_)                                                    \
  do {                                                                       \
    const int c_ = (T_) >> 3, k_ = ((T_)&7) * 32;                            \
    gl_lds16(Bft + (size_t)(c_ * 256 + srow) * SS + k_ + scol,               \
             &ring[(slot_)*8192 + ldsb]);                                    \
    gl_lds16(Bft + (size_t)(c_ * 256 + 128 + srow) * SS + k_ + scol,         \
             &ring[(slot_)*8192 + 4096 + ldsb]);                             \
  } while (0)

  STG_P2(0, 0);
  STG_P2(1, 1);

  const float inv = 1.0f / 512.0f;
  float* Ob = out + ((size_t)t * SS + mh * 128) * FF;

#pragma unroll
  for (int i = 0; i < 4; i++)
#pragma unroll
    for (int j = 0; j < 4; j++) acc[i][j] = (floatx4)0.0f;

  int slot = 0, slot2 = 2;
  for (int T = 0; T < 32; ++T) {
    if (T == 31) {
      asm volatile("s_waitcnt vmcnt(0)" ::: "memory");
    } else if (!(T >= 8 && (T & 7) < 2)) {
      asm volatile("s_waitcnt vmcnt(2)" ::: "memory");  // tile T landed
    }
    // else: skip — chunk-end stores guarantee STG(T) retired
    __builtin_amdgcn_s_barrier();

    const int k0 = (T & 7) * 32;
    const unsigned short* Bbase = &ring[slot * 8192];
    short8 af[4], bf4[4];
#pragma unroll
    for (int i = 0; i < 4; i++) {
      const int rowP = wm * 64 + i * 16 + lr;
      const unsigned off = ((unsigned)(rowP * 256 + k0 + lq * 8) * 2u) ^
                           ((unsigned)(rowP & 7) << 4);
      af[i] = *(const short8*)((const char*)P + off);
    }
#pragma unroll
    for (int j = 0; j < 4; j++)
      bf4[j] = frag_ld(Bbase, wn * 64 + j * 16 + lr, lq);
    if (T + 2 < 32) STG_P2(slot2, T + 2);

    __builtin_amdgcn_s_setprio(1);
#pragma unroll
    for (int i = 0; i < 4; i++)
#pragma unroll
      for (int j = 0; j < 4; j++)
        acc[i][j] = __builtin_amdgcn_mfma_f32_16x16x32_bf16(af[i], bf4[j],
                                                            acc[i][j], 0, 0, 0);
    __builtin_amdgcn_s_setprio(0);

    if ((T & 7) == 7) {  // f-chunk complete: write out, reset acc
      const int c = T >> 3;
#pragma unroll
      for (int i = 0; i < 4; i++) {
        const int row0 = wm * 64 + i * 16 + lq * 4;
#pragma unroll
        for (int j = 0; j < 4; j++) {
          const int col = c * 256 + wn * 64 + j * 16 + lr;
#pragma unroll
          for (int rr = 0; rr < 4; rr++)
            Ob[(size_t)(row0 + rr) * FF + col] = acc[i][j][rr] * inv;
          acc[i][j] = (floatx4)0.0f;
        }
      }
    }
    slot = (slot == 2) ? 0 : slot + 1;
    slot2 = (slot2 == 2) ? 0 : slot2 + 1;
  }
#undef STG_P2
}

// ---------------------------------------------------------------------------
extern "C" void kernel_launch(void* const* d_in, const int* in_sizes, int n_in,
                              void* d_out, int out_size, void* d_ws,
                              size_t ws_size, hipStream_t stream) {
  const float* batch = (const float*)d_in[0];
  const float* a_w   = (const float*)d_in[1];
  const float* a_b   = (const float*)d_in[2];
  const float* b_w   = (const float*)d_in[3];
  const float* b_b   = (const float*)d_in[4];
  const float* g_w   = (const float*)d_in[5];
  const float* g_b   = (const float*)d_in[6];
  float* out = (float*)d_out;

  // Workspace layout (bf16 elements).
  unsigned short* ws      = (unsigned short*)d_ws;
  unsigned short* aT      = ws;                                  // 256x1024
  unsigned short* bT      = aT + (size_t)AA * FF;                // 256x1024
  unsigned short* gT      = bT + (size_t)AA * FF;                // 1024x1024
  unsigned short* theta   = gT + (size_t)FF * FF;                // 65536x256
  unsigned short* phi     = theta + (size_t)TT * SS * AA;        // 65536x256
  unsigned short* featsT  = phi + (size_t)TT * SS * AA;          // [t][f][s]
  unsigned short* batch16 = featsT + (size_t)TT * FF * SS;       // 65536x1024

  const size_t need_b16 =
      ((size_t)2 * AA * FF + (size_t)FF * FF + (size_t)2 * TT * SS * AA +
       (size_t)TT * FF * SS + (size_t)TT * SS * FF) *
      sizeof(unsigned short);

  if (ws_size >= need_b16) {
    // One fused prep launch, R11 proj8, R8 fused attn+apply.
    k_prep<<<dim3(3584), 256, 0, stream>>>(batch, a_w, b_w, g_w, aT, bT, gT,
                                           batch16);
    k_proj8<<<dim3(1536), 512, 0, stream>>>(batch16, aT, bT, gT, a_b, b_b,
                                            g_b, theta, phi, featsT);
    k_fused2<<<dim3(512), 512, 0, stream>>>(theta, phi, featsT, out);
  } else {
    // Fallback: fp32 in-kernel staging (previous verified path).
    dim3 tb(32, 8);
    k_transpose_cvt<<<dim3(32, 8),  tb, 0, stream>>>(a_w, aT, FF, AA);
    k_transpose_cvt<<<dim3(32, 8),  tb, 0, stream>>>(b_w, bT, FF, AA);
    k_transpose_cvt<<<dim3(32, 32), tb, 0, stream>>>(g_w, gT, FF, FF);
    k_proj<<<dim3(12, 512), 256, 0, stream>>>(batch, aT, bT, gT, a_b, b_b,
                                              g_b, theta, phi, featsT);
    k_fused2<<<dim3(512), 512, 0, stream>>>(theta, phi, featsT, out);
  }
}